// Round 5
// baseline (102.893 us; speedup 1.0000x reference)
//
#include <hip/hip_runtime.h>
#include <cstddef>

typedef _Float16 h2    __attribute__((ext_vector_type(2)));
typedef _Float16 half8 __attribute__((ext_vector_type(8)));
typedef float    f32x4 __attribute__((ext_vector_type(4)));

#define CH    192
#define CWID  640
#define IMG_H 384
#define IMG_W 1280
#define TW    128
#define GR    224    // g rows staged
#define RAWC  179    // 66 fl cols + 113 g cols

struct __attribute__((packed, aligned(4))) f3u { float x, y, z; };

__device__ __forceinline__ float fastrcp(float x) {
#if __has_builtin(__builtin_amdgcn_rcpf)
  return __builtin_amdgcn_rcpf(x);
#else
  return 1.0f / x;
#endif
}

// ---------------- Kernel 1: 3x3 stride-2 SAME conv + bias + ReLU -> f16 ----------------
// 256 threads = 128 ow x 2 oh. Input tile (5 rows x 258 cols x 3ch) staged in LDS with
// zero-padded bounds (fma with 0 is exact == reference's skip).
__global__ __launch_bounds__(256, 4)
void conv_relu_kernel(const float* __restrict__ xl, const float* __restrict__ xr,
                      const float* __restrict__ Wt, const float* __restrict__ bias,
                      _Float16* __restrict__ Fc) {
  __shared__ float wl[864];
  __shared__ float bl[32];
  __shared__ float lin[5 * 776];   // 258 cols * 3ch = 774, padded to 776 (16B rows)

  const int tid = threadIdx.x;
  for (int t = tid; t < 864; t += 256) wl[t] = Wt[t];
  if (tid < 32) bl[tid] = bias[tid];

  const int ow0 = blockIdx.x * 128;
  const int by  = blockIdx.y;          // oh pair index (oh = 2*by + doh)
  const int bb  = blockIdx.z;
  const int ir0 = by * 4;              // input row base
  const int cb  = ow0 * 2;             // input col base
  const float* src = (bb < 2) ? (xl + (size_t)bb * IMG_H * IMG_W * 3)
                              : (xr + (size_t)(bb - 2) * IMG_H * IMG_W * 3);

  #pragma unroll
  for (int r = 0; r < 5; ++r) {
    const int ir = ir0 + r;
    for (int c = tid; c < 258; c += 256) {
      const int col = cb + c;
      f3u v = {0.f, 0.f, 0.f};
      if (ir < IMG_H && col < IMG_W)
        v = *(const f3u*)(src + ((size_t)ir * IMG_W + col) * 3);
      float* d = &lin[r * 776 + c * 3];
      d[0] = v.x; d[1] = v.y; d[2] = v.z;
    }
  }
  __syncthreads();

  const int dow = tid & 127;
  const int doh = tid >> 7;
  float acc[32];
  #pragma unroll
  for (int c = 0; c < 32; ++c) acc[c] = bl[c];

  #pragma unroll
  for (int kh = 0; kh < 3; ++kh) {
    const float* row = &lin[(2 * doh + kh) * 776];
    #pragma unroll
    for (int kw = 0; kw < 3; ++kw) {
      const float* px = row + (2 * dow + kw) * 3;
      #pragma unroll
      for (int ci = 0; ci < 3; ++ci) {
        const float v = px[ci];
        const float* wp = &wl[((kh * 3 + kw) * 3 + ci) * 32];
        #pragma unroll
        for (int c8 = 0; c8 < 8; ++c8) {
          const float4 w4 = *(const float4*)(wp + c8 * 4);
          acc[c8 * 4 + 0] = fmaf(v, w4.x, acc[c8 * 4 + 0]);
          acc[c8 * 4 + 1] = fmaf(v, w4.y, acc[c8 * 4 + 1]);
          acc[c8 * 4 + 2] = fmaf(v, w4.z, acc[c8 * 4 + 2]);
          acc[c8 * 4 + 3] = fmaf(v, w4.w, acc[c8 * 4 + 3]);
        }
      }
    }
  }

  const int oh = by * 2 + doh;
  const size_t g = ((size_t)bb * CH + oh) * CWID + (ow0 + dow);
  _Float16 hv[32];
  #pragma unroll
  for (int c = 0; c < 32; ++c) hv[c] = (_Float16)fmaxf(acc[c], 0.f);
  half8* dst = (half8*)(Fc + g * 32);
  #pragma unroll
  for (int q = 0; q < 4; ++q) {
    half8 o;
    #pragma unroll
    for (int e = 0; e < 8; ++e) o[e] = hv[q * 8 + e];
    dst[q] = o;
  }
}

// ------- Kernel 2: f16 MFMA cost volume + soft-argmin -------
__global__ __launch_bounds__(256, 4)
void disparity_mfma_kernel(const _Float16* __restrict__ Fc, float* __restrict__ out) {
  __shared__ alignas(16) _Float16 raw[RAWC * 32];   // 11.2 KB, vertically blended
  __shared__ alignas(16) _Float16 flH[8 * 512];     // 8 tiles [16][32] f16
  __shared__ alignas(16) _Float16 gH[14 * 512];     // 14 tiles
  __shared__ alignas(16) float As[TW];
  __shared__ alignas(16) float Bs[GR];

  const int tid = threadIdx.x;
  const int w0  = blockIdx.x * TW;
  const int h   = blockIdx.y;
  const int bz  = blockIdx.z;

  // vertical bilinear params (half-pixel, clamped)
  const int hk = h >> 1;
  int r0, r1; float wv0;
  if (h & 1) { r0 = hk; r1 = (hk + 1 > CH - 1) ? CH - 1 : hk + 1; wv0 = 0.75f; }
  else       { r0 = (hk - 1 < 0) ? 0 : hk - 1; r1 = hk;           wv0 = 0.25f; }
  const half8 w0v = (half8)(_Float16)wv0;
  const half8 w1v = (half8)(_Float16)(1.0f - wv0);

  const int vbaseL = (w0 >> 1) + 639;  // fl raw region (t 0..65)
  const int vbaseR = (w0 >> 1) + 592;  // g raw region (t 66..178)

  char* const rawB = (char*)raw;

  // scalar row bases (hoisted 64-bit math)
  const char* const bL0 = (const char*)(Fc + ((size_t)bz * CH + r0) * CWID * 32);
  const char* const bL1 = (const char*)(Fc + ((size_t)bz * CH + r1) * CWID * 32);
  const char* const bR0 = (const char*)(Fc + ((size_t)(bz + 2) * CH + r0) * CWID * 32);
  const char* const bR1 = (const char*)(Fc + ((size_t)(bz + 2) * CH + r1) * CWID * 32);

  // ---- Phase 0: stage + vertical blend; col = (vbase+t) wrapped into [0,640) ----
  for (int task = tid; task < RAWC * 4; task += 256) {
    const int t   = task >> 2;
    const int c16 = task & 3;
    const bool isfl = t < 66;
    int v = isfl ? (vbaseL + t) : (vbaseR + t - 66);   // in [592, 1280]
    v -= (v >= 640) ? 640 : 0;
    v -= (v >= 640) ? 640 : 0;                          // 1280 -> 0 (roll wrap)
    const char* p0 = isfl ? bL0 : bR0;
    const char* p1 = isfl ? bL1 : bR1;
    const int off = (v << 6) + (c16 << 4);
    const half8 a0 = *(const half8*)(p0 + off);
    const half8 a1 = *(const half8*)(p1 + off);
    const half8 vv = a0 * w0v + a1 * w1v;
    *(half8*)(rawB + t * 64 + ((c16 ^ (t & 3)) << 4)) = vv;
  }
  __syncthreads();

  // ---- Phase 1: horizontal blend + MFMA tiles + norms (same f16 values) ----
  const _Float16 h75 = (_Float16)0.75f, h25 = (_Float16)0.25f;
  for (int row = tid; row < TW + GR; row += 256) {
    const bool isfl = row < TW;
    const int r  = isfl ? row : row - TW;
    const int uv = isfl ? (w0 + r) : (w0 - 95 + r);
    const int uact = uv < 0 ? uv + IMG_W : (uv >= IMG_W ? uv - IMG_W : uv);
    const int up = uv + IMG_W;                       // positive, same parity
    const int vm0 = (up - 1) >> 1;                   // branch-free taps
    int t0 = vm0 - (isfl ? vbaseL : (vbaseR - 66));
    int t1 = t0 + 1;
    if (uact == 0)         t0 = t1;   // left-edge clamp
    if (uact == IMG_W - 1) t1 = t0;   // right-edge clamp
    const _Float16 hw0 = (up & 1) ? h75 : h25;
    const _Float16 hw1 = (up & 1) ? h25 : h75;
    const half8 h0v = (half8)hw0;
    const half8 h1v = (half8)hw1;
    const char* r0p = rawB + t0 * 64;
    const char* r1p = rawB + t1 * 64;
    const int k0s = t0 & 3, k1s = t1 & 3;
    const int rr  = r & 15;
    char* dstB = (char*)(isfl ? flH : gH) + (r >> 4) * 1024 + rr * 64;
    float s = 0.f;
    #pragma unroll
    for (int c16 = 0; c16 < 4; ++c16) {
      const half8 a = *(const half8*)(r0p + ((c16 ^ k0s) << 4));
      const half8 b = *(const half8*)(r1p + ((c16 ^ k1s) << 4));
      const half8 v = a * h0v + b * h1v;
      #pragma unroll
      for (int e = 0; e < 4; ++e) {
        h2 pe = {v[2 * e], v[2 * e + 1]};
#if __has_builtin(__builtin_amdgcn_fdot2)
        s = __builtin_amdgcn_fdot2(pe, pe, s, false);
#else
        s += (float)pe[0] * (float)pe[0] + (float)pe[1] * (float)pe[1];
#endif
      }
      *(half8*)(dstB + ((c16 ^ (rr & 3)) << 4)) = v;
    }
    if (isfl) As[r] = s; else Bs[r] = s;
  }
  __syncthreads();

  // ---- Phase 2: MFMA band + per-pixel soft-argmin ----
  const int lane = tid & 63;
  const int wid  = tid >> 6;
  const int n  = lane & 15;   // fl row within tile (C col)
  const int gq = lane >> 4;   // k-slice / C row group
  const int foffB = n * 64 + ((gq ^ (n & 3)) << 4);

  #pragma unroll
  for (int pp = 0; pp < 2; ++pp) {
    const int p = wid * 2 + pp;          // i-tile 0..7
    const half8 bfrag = *(const half8*)((const char*)flH + p * 1024 + foffB);
    f32x4 acc[7];
    #pragma unroll
    for (int dq = 0; dq < 7; ++dq) {
      const half8 afrag = *(const half8*)((const char*)gH + (p + dq) * 1024 + foffB);
      f32x4 z = {0.f, 0.f, 0.f, 0.f};
      acc[dq] = __builtin_amdgcn_mfma_f32_16x16x32_f16(afrag, bfrag, z, 0, 0, 0);
    }

    // pass 1: cost + min/max. Invalid band cells (only dq 0 and 6) stored as +3e38
    // so pass 2 needs NO mask: exp2(-inf) = 0.
    const float Ai = As[p * 16 + n];
    float cv[7][4];
    float mn = 3.0e38f, mx = -3.0e38f;
    #pragma unroll
    for (int dq = 0; dq < 7; ++dq) {
      const f32x4 b4 = *(const f32x4*)(&Bs[(p + dq) * 16 + gq * 4]);
      #pragma unroll
      for (int rg = 0; rg < 4; ++rg) {
        const int m = gq * 4 + rg;
        const float cc = fmaf(-2.f, acc[dq][rg], Ai + b4[rg]);
        const bool valid = (dq != 0 || m >= n) && (dq != 6 || m < n);
        const float cm = valid ? cc : 3.0e38f;
        cv[dq][rg] = cm;
        mn = fminf(mn, cm);
        mx = fmaxf(mx, valid ? cc : -3.0e38f);
      }
    }
    mn = fminf(mn, __shfl_xor(mn, 16, 64));
    mn = fminf(mn, __shfl_xor(mn, 32, 64));
    mx = fmaxf(mx, __shfl_xor(mx, 16, 64));
    mx = fmaxf(mx, __shfl_xor(mx, 32, 64));

    // pass 2: select-free softmax accumulation (log2e folded, rcp instead of div)
    const float ralpha = 177.0f * 1.4426950408889634f * fastrcp(mx);
    const float na   = -ralpha;
    const float base = ralpha * mn;
    float sw = 0.f, sdw = 0.f;
    #pragma unroll
    for (int dq = 0; dq < 7; ++dq) {
      #pragma unroll
      for (int rg = 0; rg < 4; ++rg) {
        const int m = gq * 4 + rg;
        const float wgt = exp2f(fmaf(na, cv[dq][rg], base));  // 0 for masked cells
        sw += wgt;
        const float kf = (float)(95 - (dq * 16 + m - n));     // d = 95 - k
        sdw = fmaf(kf, wgt, sdw);
      }
    }
    sw  += __shfl_xor(sw, 16, 64);  sw  += __shfl_xor(sw, 32, 64);
    sdw += __shfl_xor(sdw, 16, 64); sdw += __shfl_xor(sdw, 32, 64);
    if (gq == 0)
      out[((size_t)bz * IMG_H + h) * IMG_W + w0 + p * 16 + n] = sdw * fastrcp(sw);
  }
}

extern "C" void kernel_launch(void* const* d_in, const int* in_sizes, int n_in,
                              void* d_out, int out_size, void* d_ws, size_t ws_size,
                              hipStream_t stream) {
  (void)in_sizes; (void)n_in; (void)out_size; (void)ws_size;
  const float* xl   = (const float*)d_in[0];
  const float* xr   = (const float*)d_in[1];
  const float* Wt   = (const float*)d_in[2];
  const float* bias = (const float*)d_in[3];
  _Float16* Fc = (_Float16*)d_ws;   // conv features [4,192,640,32] f16 = 31.5 MB
  float* out = (float*)d_out;       // [2,384,1280] f32

  hipLaunchKernelGGL(conv_relu_kernel, dim3(5, 96, 4), dim3(256), 0, stream,
                     xl, xr, Wt, bias, Fc);
  hipLaunchKernelGGL(disparity_mfma_kernel, dim3(IMG_W / TW, IMG_H, 2), dim3(256), 0, stream,
                     Fc, out);
}